// Round 14
// baseline (212.453 us; speedup 1.0000x reference)
//
#include <hip/hip_runtime.h>

typedef unsigned short u16;
typedef float f32x4 __attribute__((ext_vector_type(4)));
typedef short bf16x8 __attribute__((ext_vector_type(8)));

constexpr int SH = 9;          // 512 nodes per bucket
constexpr int NB = 1 << SH;    // 512
constexpr int TILE = 4096;     // edges per partition block

__device__ inline float bf2f(u16 u) {
  union { unsigned int i; float f; } c;
  c.i = ((unsigned int)u) << 16;
  return c.f;
}
__device__ inline u16 f2bf(float f) {
  union { float f; unsigned int i; } c;
  c.f = f;
  unsigned int r = c.i + 0x7fff + ((c.i >> 16) & 1);  // RNE
  return (u16)(r >> 16);
}

union V8 {
  bf16x8 v;
  short s[8];
  u16 u[8];
  int i[4];
};

// ---------------- graph build: tiled counting sort (r12 proven form) ------------

__global__ void __launch_bounds__(256) k_hist(const int* __restrict__ dst,
                                              int* __restrict__ ghist, int E,
                                              int nblk, int nbk) {
  __shared__ int lcnt[NB];
  int t = threadIdx.x, blk = blockIdx.x;
  for (int i = t; i < nbk; i += 256) lcnt[i] = 0;
  __syncthreads();
  int beg = blk * TILE, end = min(beg + TILE, E);
  for (int e = beg + t; e < end; e += 256) atomicAdd(&lcnt[dst[e] >> SH], 1);
  __syncthreads();
  for (int i = t; i < nbk; i += 256) ghist[i * nblk + blk] = lcnt[i];
}

__global__ void __launch_bounds__(256) k_scanA(int* __restrict__ ghist,
                                               int* __restrict__ bsum, int nblk) {
  __shared__ int sc[256];
  int i = blockIdx.x, t = threadIdx.x;
  int* row = ghist + (size_t)i * nblk;
  int e0 = 2 * t, e1 = 2 * t + 1;
  int a0 = (e0 < nblk) ? row[e0] : 0;
  int a1 = (e1 < nblk) ? row[e1] : 0;
  int s = a0 + a1;
  sc[t] = s;
  __syncthreads();
  for (int o = 1; o < 256; o <<= 1) {
    int x = (t >= o) ? sc[t - o] : 0;
    __syncthreads();
    sc[t] += x;
    __syncthreads();
  }
  int base = sc[t] - s;  // exclusive
  if (e0 < nblk) row[e0] = base;
  if (e1 < nblk) row[e1] = base + a0;
  if (t == 255) bsum[i] = sc[255];
}

__global__ void __launch_bounds__(256) k_part(const int* __restrict__ src,
                                              const int* __restrict__ dst,
                                              const int* __restrict__ goff,
                                              const int* __restrict__ bsum,
                                              int* __restrict__ ebuf, int E,
                                              int nblk, int nbk) {
  __shared__ int lcur[NB];
  __shared__ int sb[256];
  int t = threadIdx.x, blk = blockIdx.x;
  int v = (t < nbk) ? bsum[t] : 0;
  sb[t] = v;
  __syncthreads();
  for (int o = 1; o < 256; o <<= 1) {
    int x = (t >= o) ? sb[t - o] : 0;
    __syncthreads();
    sb[t] += x;
    __syncthreads();
  }
  for (int i = t; i < nbk; i += 256)
    lcur[i] = goff[(size_t)i * nblk + blk] + (i ? sb[i - 1] : 0);
  __syncthreads();
  int beg = blk * TILE, end = min(beg + TILE, E);
  for (int e = beg + t; e < end; e += 256) {
    int s = src[e], d = dst[e];
    int p = atomicAdd(&lcur[d >> SH], 1);
    ebuf[p] = s | ((d & (NB - 1)) << 20);
  }
}

__global__ void __launch_bounds__(256) k_refine(
    const int* __restrict__ ebuf, const int* __restrict__ goff,
    const int* __restrict__ bsum, int* __restrict__ rowptr,
    int* __restrict__ colsrc, float* __restrict__ dinv,
    int n, int nbk, int nblk, int E) {
  __shared__ int cnt[NB];
  __shared__ int cur[NB];
  __shared__ int sc[256];
  __shared__ int bex[256];
  int b = blockIdx.x, t = threadIdx.x;
  {
    int v = (t < nbk) ? bsum[t] : 0;
    bex[t] = v;
    __syncthreads();
    for (int o = 1; o < 256; o <<= 1) {
      int x = (t >= o) ? bex[t - o] : 0;
      __syncthreads();
      bex[t] += x;
      __syncthreads();
    }
  }
  int beg = goff[(size_t)b * nblk] + (b ? bex[b - 1] : 0);
  int end = (b + 1 < nbk) ? goff[(size_t)(b + 1) * nblk] + bex[b] : E;
  cnt[t] = 0;
  cnt[t + 256] = 0;
  __syncthreads();
  for (int i = beg + t; i < end; i += 256) atomicAdd(&cnt[ebuf[i] >> 20], 1);
  __syncthreads();
  int c0 = cnt[2 * t], c1 = cnt[2 * t + 1];
  int a = c0 + c1;
  sc[t] = a;
  __syncthreads();
  for (int o = 1; o < 256; o <<= 1) {
    int x = (t >= o) ? sc[t - o] : 0;
    __syncthreads();
    sc[t] += x;
    __syncthreads();
  }
  int base0 = beg + sc[t] - a;
  int base1 = base0 + c0;
  int node0 = b << SH;
  int n0 = node0 + 2 * t, n1 = n0 + 1;
  cur[2 * t] = base0;
  cur[2 * t + 1] = base1;
  if (n0 <= n) rowptr[n0] = base0;
  if (n1 <= n) rowptr[n1] = base1;
  if (n0 < n) dinv[n0] = rsqrtf((float)(c0 + 1));
  if (n1 < n) dinv[n1] = rsqrtf((float)(c1 + 1));
  if (b == nbk - 1 && t == 0) rowptr[n] = E;
  __syncthreads();
  for (int i = beg + t; i < end; i += 256) {
    int w = ebuf[i];
    int p = atomicAdd(&cur[w >> 20], 1);
    colsrc[p] = w & 0xFFFFF;
  }
}

// ---------------- MFMA dense transform + optional FC slice -----------------
// g planes: plane nc holds cols nc*16..nc*16+15 of all rows, contiguous (n*16 u16).

template <int KC, int FOUT, bool BF16IN, int FCROW0, int FCROWS, int MODE>
__global__ void __launch_bounds__(256) k_xform(
    const void* __restrict__ xin, const float* __restrict__ Wg,
    const float* __restrict__ dinv, u16* __restrict__ g,
    const float* __restrict__ Wfc, float* __restrict__ out, int n) {
  constexpr int FIN = KC * 32;
  constexpr int NC = FOUT / 16;
  constexpr int ASLOTS = 8 * KC * 64;
  constexpr int WSLOTS = KC * NC * 64;
  constexpr int WFS = (FCROWS > 0) ? KC * 64 : 1;
  __shared__ short xa[ASLOTS * 8];
  __shared__ short wb[WSLOTS * 8];
  __shared__ short wfb[WFS * 8];

  int t = threadIdx.x;
  int r0 = blockIdx.x * 128;

  for (int s = t; s < WSLOTS; s += 256) {
    int lane = s & 63, q = s >> 6;
    int nc = q % NC, kc = q / NC;
    int col = nc * 16 + (lane & 15);
    int kr = kc * 32 + (lane >> 4) * 8;
    V8 v;
#pragma unroll
    for (int j = 0; j < 8; ++j) v.s[j] = (short)f2bf(Wg[(kr + j) * FOUT + col]);
    *(bf16x8*)&wb[s * 8] = v.v;
  }
  if constexpr (FCROWS > 0) {
    for (int s = t; s < WFS; s += 256) {
      int lane = s & 63, kc = s >> 6;
      int col = lane & 15;
      int kr = kc * 32 + (lane >> 4) * 8;
      V8 v;
#pragma unroll
      for (int j = 0; j < 8; ++j)
        v.s[j] = (kr + j < FCROWS) ? (short)f2bf(Wfc[(FCROW0 + kr + j) * 16 + col]) : (short)0;
      *(bf16x8*)&wfb[s * 8] = v.v;
    }
  }

  for (int s = t; s < ASLOTS; s += 256) {
    int lane = s & 63, q = s >> 6;
    int kc = q % KC, mtile = q / KC;
    int row = mtile * 16 + (lane & 15);
    int k = kc * 32 + (lane >> 4) * 8;
    int gr = r0 + row;
    V8 v;
    if (gr < n) {
      if constexpr (BF16IN) {
        v.v = *(const bf16x8*)((const u16*)xin + (size_t)gr * FIN + k);
      } else {
        const float* xf = (const float*)xin + (size_t)gr * FIN + k;
        float4 p = *(const float4*)xf;
        float4 q4 = *(const float4*)(xf + 4);
        v.s[0] = (short)f2bf(p.x); v.s[1] = (short)f2bf(p.y);
        v.s[2] = (short)f2bf(p.z); v.s[3] = (short)f2bf(p.w);
        v.s[4] = (short)f2bf(q4.x); v.s[5] = (short)f2bf(q4.y);
        v.s[6] = (short)f2bf(q4.z); v.s[7] = (short)f2bf(q4.w);
      }
    } else {
      for (int j = 0; j < 8; ++j) v.s[j] = 0;
    }
    *(bf16x8*)&xa[s * 8] = v.v;
  }
  __syncthreads();

  int ln = t & 63, wv = t >> 6;
  int m0 = wv * 2;

  bf16x8 bf[KC * NC];
#pragma unroll
  for (int i = 0; i < KC * NC; ++i) bf[i] = *(const bf16x8*)&wb[(i * 64 + ln) * 8];
  bf16x8 wff[(FCROWS > 0) ? KC : 1];
  if constexpr (FCROWS > 0) {
#pragma unroll
    for (int i = 0; i < KC; ++i) wff[i] = *(const bf16x8*)&wfb[(i * 64 + ln) * 8];
  }

  f32x4 acc[2][NC];
  f32x4 accF[2];
#pragma unroll
  for (int i = 0; i < 2; ++i) {
    accF[i] = {0.f, 0.f, 0.f, 0.f};
#pragma unroll
    for (int j = 0; j < NC; ++j) acc[i][j] = {0.f, 0.f, 0.f, 0.f};
  }

#pragma unroll
  for (int kc = 0; kc < KC; ++kc) {
    bf16x8 a0 = *(const bf16x8*)&xa[(((m0 + 0) * KC + kc) * 64 + ln) * 8];
    bf16x8 a1 = *(const bf16x8*)&xa[(((m0 + 1) * KC + kc) * 64 + ln) * 8];
#pragma unroll
    for (int nc = 0; nc < NC; ++nc) {
      acc[0][nc] = __builtin_amdgcn_mfma_f32_16x16x32_bf16(a0, bf[kc * NC + nc], acc[0][nc], 0, 0, 0);
      acc[1][nc] = __builtin_amdgcn_mfma_f32_16x16x32_bf16(a1, bf[kc * NC + nc], acc[1][nc], 0, 0, 0);
    }
    if constexpr (FCROWS > 0) {
      accF[0] = __builtin_amdgcn_mfma_f32_16x16x32_bf16(a0, wff[kc], accF[0], 0, 0, 0);
      accF[1] = __builtin_amdgcn_mfma_f32_16x16x32_bf16(a1, wff[kc], accF[1], 0, 0, 0);
    }
  }

  int colb = ln & 15, rq = ln >> 4;
#pragma unroll
  for (int mt2 = 0; mt2 < 2; ++mt2) {
#pragma unroll
    for (int reg = 0; reg < 4; ++reg) {
      int gr = r0 + (m0 + mt2) * 16 + rq * 4 + reg;
      if (gr < n) {
        float di = dinv[gr];
#pragma unroll
        for (int nc = 0; nc < NC; ++nc)  // plane layout
          g[((size_t)nc * n + gr) * 16 + colb] = f2bf(acc[mt2][nc][reg] * di);
        if constexpr (FCROWS > 0) {
          size_t oi = (size_t)gr * 16 + colb;
          if constexpr (MODE == 0) out[oi] = accF[mt2][reg];
          else out[oi] += accF[mt2][reg];
        }
      }
    }
  }
}

// ---------------- plane gather + finalize (L2-resident 3.2MB plane) -------------
// One 16-col plane per dispatch: 2 lanes/node (16B each), 32 nodes/wave, 4-way
// unroll = 128 concurrent 32B row-reads per wave. fout pre-offset by plane*16.

template <int FTOT>
__global__ void __launch_bounds__(256) k_gplane(
    const u16* __restrict__ plane, const int* __restrict__ rowptr,
    const int* __restrict__ colsrc, const float* __restrict__ dinv,
    const float* __restrict__ bias16, u16* __restrict__ fout, int n) {
  int t = threadIdx.x;
  int ln = t & 63, wib = t >> 6;
  int lanein = ln & 1, grp = ln >> 1;  // 32 nodes/wave
  int f0 = lanein * 8;
  float bb[8];
#pragma unroll
  for (int j = 0; j < 8; ++j) bb[j] = bias16[f0 + j];
  int gw = blockIdx.x * (blockDim.x >> 6) + wib;
  int nwaves = (gridDim.x * blockDim.x) >> 6;
  for (int node = gw * 32 + grp; node < n; node += nwaves * 32) {
    int b = rowptr[node], e = rowptr[node + 1];
    float p0[8], p1[8], p2[8], p3[8];
    {
      V8 u;
      u.v = *(const bf16x8*)&plane[(size_t)node * 16 + f0];  // self-loop
#pragma unroll
      for (int j = 0; j < 8; ++j) {
        p0[j] = bf2f(u.u[j]);
        p1[j] = 0.f; p2[j] = 0.f; p3[j] = 0.f;
      }
    }
    int i = b;
    for (; i + 4 <= e; i += 4) {
      int s0 = colsrc[i + 0], s1 = colsrc[i + 1];
      int s2 = colsrc[i + 2], s3 = colsrc[i + 3];
      V8 u0, u1, u2, u3;
      u0.v = *(const bf16x8*)&plane[(size_t)s0 * 16 + f0];
      u1.v = *(const bf16x8*)&plane[(size_t)s1 * 16 + f0];
      u2.v = *(const bf16x8*)&plane[(size_t)s2 * 16 + f0];
      u3.v = *(const bf16x8*)&plane[(size_t)s3 * 16 + f0];
#pragma unroll
      for (int j = 0; j < 8; ++j) {
        p0[j] += bf2f(u0.u[j]);
        p1[j] += bf2f(u1.u[j]);
        p2[j] += bf2f(u2.u[j]);
        p3[j] += bf2f(u3.u[j]);
      }
    }
    for (; i < e; ++i) {
      int s = colsrc[i];
      V8 u;
      u.v = *(const bf16x8*)&plane[(size_t)s * 16 + f0];
#pragma unroll
      for (int j = 0; j < 8; ++j) p1[j] += bf2f(u.u[j]);
    }
    float di = dinv[node];
    V8 o;
#pragma unroll
    for (int j = 0; j < 8; ++j) {
      float a = (p0[j] + p1[j]) + (p2[j] + p3[j]);
      o.u[j] = f2bf(fmaxf(fmaf(a, di, bb[j]), 0.f));
    }
    *(bf16x8*)&fout[(size_t)node * FTOT + f0] = o.v;
  }
}

// ---------------- layer-3 gather + in-wave FC tail ------------------------------

__global__ void __launch_bounds__(256) k_gather_fc(
    const u16* __restrict__ g3, const int* __restrict__ rowptr,
    const int* __restrict__ colsrc, const float* __restrict__ dinv,
    const float* __restrict__ b3, const float* __restrict__ Wfc,
    const float* __restrict__ bfc, float* __restrict__ out, int n) {
  __shared__ short wfb[64 * 8];
  int t = threadIdx.x;
  for (int s = t; s < 64; s += 256) {
    int lane = s & 63;
    int col = lane & 15;
    int kr = (lane >> 4) * 8;
    V8 v;
#pragma unroll
    for (int j = 0; j < 8; ++j)
      v.s[j] = (kr + j < 16) ? (short)f2bf(Wfc[(96 + kr + j) * 16 + col]) : (short)0;
    *(bf16x8*)&wfb[s * 8] = v.v;
  }
  __syncthreads();

  int ln = t & 63, wv = t >> 6;
  bf16x8 wff = *(const bf16x8*)&wfb[ln * 8];
  int lanein = ln & 1, grp = ln >> 1;
  int f0 = lanein * 8;
  float bb[8];
#pragma unroll
  for (int j = 0; j < 8; ++j) bb[j] = b3[f0 + j];
  int colb = ln & 15, rq = ln >> 4, kq = ln >> 4;
  float bfcc = bfc[colb];

  int wid = blockIdx.x * 4 + wv;
  int nw = gridDim.x * 4;
  int nch = (n + 31) / 32;

  for (int ch = wid; ch < nch; ch += nw) {
    int gr = ch * 32 + grp;
    V8 o;
    if (gr < n) {
      int b = rowptr[gr], e = rowptr[gr + 1];
      float p0[8], p1[8], p2[8], p3[8];
      {
        V8 u;
        u.v = *(const bf16x8*)&g3[(size_t)gr * 16 + f0];
#pragma unroll
        for (int j = 0; j < 8; ++j) {
          p0[j] = bf2f(u.u[j]);
          p1[j] = 0.f; p2[j] = 0.f; p3[j] = 0.f;
        }
      }
      int i = b;
      for (; i + 4 <= e; i += 4) {
        int s0 = colsrc[i + 0], s1 = colsrc[i + 1];
        int s2 = colsrc[i + 2], s3 = colsrc[i + 3];
        V8 u0, u1, u2, u3;
        u0.v = *(const bf16x8*)&g3[(size_t)s0 * 16 + f0];
        u1.v = *(const bf16x8*)&g3[(size_t)s1 * 16 + f0];
        u2.v = *(const bf16x8*)&g3[(size_t)s2 * 16 + f0];
        u3.v = *(const bf16x8*)&g3[(size_t)s3 * 16 + f0];
#pragma unroll
        for (int j = 0; j < 8; ++j) {
          p0[j] += bf2f(u0.u[j]);
          p1[j] += bf2f(u1.u[j]);
          p2[j] += bf2f(u2.u[j]);
          p3[j] += bf2f(u3.u[j]);
        }
      }
      for (; i < e; ++i) {
        int s = colsrc[i];
        V8 u;
        u.v = *(const bf16x8*)&g3[(size_t)s * 16 + f0];
#pragma unroll
        for (int j = 0; j < 8; ++j) p1[j] += bf2f(u.u[j]);
      }
      float di = dinv[gr];
#pragma unroll
      for (int j = 0; j < 8; ++j) {
        float a = (p0[j] + p1[j]) + (p2[j] + p3[j]);
        o.u[j] = f2bf(fmaxf(fmaf(a, di, bb[j]), 0.f));
      }
    } else {
#pragma unroll
      for (int j = 0; j < 8; ++j) o.s[j] = 0;
    }

#pragma unroll
    for (int tt = 0; tt < 2; ++tt) {
      int sl4 = (((ln & 15) + tt * 16) * 2 + (kq & 1)) * 4;
      V8 A;
#pragma unroll
      for (int d = 0; d < 4; ++d)
        A.i[d] = __builtin_amdgcn_ds_bpermute(sl4, o.i[d]);
      if (kq >= 2) {
#pragma unroll
        for (int j = 0; j < 8; ++j) A.s[j] = 0;
      }
      f32x4 acc = {0.f, 0.f, 0.f, 0.f};
      acc = __builtin_amdgcn_mfma_f32_16x16x32_bf16(A.v, wff, acc, 0, 0, 0);
#pragma unroll
      for (int reg = 0; reg < 4; ++reg) {
        int go = ch * 32 + tt * 16 + rq * 4 + reg;
        if (go < n) {
          size_t oi = (size_t)go * 16 + colb;
          out[oi] = fmaxf(out[oi] + acc[reg] + bfcc, 0.f);
        }
      }
    }
  }
}

// ---------------- launch ----------------

extern "C" void kernel_launch(void* const* d_in, const int* in_sizes, int n_in,
                              void* d_out, int out_size, void* d_ws, size_t ws_size,
                              hipStream_t stream) {
  const int* edges = (const int*)d_in[0];
  const float* feat = (const float*)d_in[1];
  const float* W1 = (const float*)d_in[2];
  const float* b1 = (const float*)d_in[3];
  const float* W2 = (const float*)d_in[4];
  const float* b2 = (const float*)d_in[5];
  const float* W3 = (const float*)d_in[6];
  const float* b3 = (const float*)d_in[7];
  const float* Wfc = (const float*)d_in[8];
  const float* bfc = (const float*)d_in[9];
  float* out = (float*)d_out;

  const int E = in_sizes[0] / 2;
  const int n = in_sizes[1] / 128;
  const int* srcp = edges;
  const int* dstp = edges + E;
  const int nbk = (n + NB - 1) >> SH;          // 196 (<=256)
  const int nblk = (E + TILE - 1) / TILE;      // 391 (<=512)

  char* w = (char*)d_ws;
  auto carve = [&](size_t bytes) {
    void* p = (void*)w;
    w += (bytes + 255) & ~(size_t)255;
    return p;
  };
  int* ghist = (int*)carve((size_t)nbk * nblk * 4);
  int* bsum = (int*)carve(256 * 4);
  int* rowptr = (int*)carve(((size_t)n + 1) * 4);
  float* dinv = (float*)carve((size_t)n * 4);
  int* colsrc = (int*)carve((size_t)E * 4);
  // bufA: ebuf (E*4B) -> g1 (4 planes, n*128B) -> f2 (n*64B)
  size_t bigA = (size_t)E * 4 > (size_t)n * 128 ? (size_t)E * 4 : (size_t)n * 128;
  void* pA = carve(bigA);
  int* ebuf = (int*)pA;
  u16* g1 = (u16*)pA;
  u16* f2 = (u16*)pA;
  // bufB: f1 (n*128B) -> g3 (n*32B)
  void* pB = carve((size_t)n * 128);
  u16* f1 = (u16*)pB;
  u16* g3 = (u16*)pB;
  u16* g2 = (u16*)carve((size_t)n * 64);  // 2 planes

  k_hist<<<nblk, 256, 0, stream>>>(dstp, ghist, E, nblk, nbk);
  k_scanA<<<nbk, 256, 0, stream>>>(ghist, bsum, nblk);
  k_part<<<nblk, 256, 0, stream>>>(srcp, dstp, ghist, bsum, ebuf, E, nblk, nbk);
  k_refine<<<nbk, 256, 0, stream>>>(ebuf, ghist, bsum, rowptr, colsrc, dinv, n, nbk, nblk, E);

  const int xb = (n + 127) / 128;  // 782
  const int gp = (n + 127) / 128;  // 782: 4 waves x 32 nodes = 128 nodes/block

  // layer 1 transform: feat -> g1 planes
  k_xform<4, 64, false, 0, 0, 0><<<xb, 256, 0, stream>>>(
      feat, W1, dinv, g1, (const float*)nullptr, (float*)nullptr, n);
  // gather 1: four L2-resident plane passes, g1 -> f1
  for (int p = 0; p < 4; ++p)
    k_gplane<64><<<gp, 256, 0, stream>>>(
        g1 + (size_t)p * n * 16, rowptr, colsrc, dinv, b1 + p * 16, f1 + p * 16, n);
  // transform 2 + FC slice 1: f1 -> g2 planes ; out = f1 @ Wfc[0:64]
  k_xform<2, 32, true, 0, 64, 0><<<xb, 256, 0, stream>>>(
      f1, W2, dinv, g2, Wfc, out, n);
  // gather 2: two plane passes, g2 -> f2
  for (int p = 0; p < 2; ++p)
    k_gplane<32><<<gp, 256, 0, stream>>>(
        g2 + (size_t)p * n * 16, rowptr, colsrc, dinv, b2 + p * 16, f2 + p * 16, n);
  // transform 3 + FC slice 2: f2 -> g3 ; out += f2 @ Wfc[64:96]
  k_xform<1, 16, true, 64, 32, 1><<<xb, 256, 0, stream>>>(
      f2, W3, dinv, g3, Wfc, out, n);
  // gather 3 + FC tail: out = relu(out + f3 @ Wfc[96:112] + bfc)
  k_gather_fc<<<xb, 256, 0, stream>>>(g3, rowptr, colsrc, dinv, b3, Wfc, bfc, out, n);
}

// Round 15
// 155.730 us; speedup vs baseline: 1.3642x; 1.3642x over previous
//
#include <hip/hip_runtime.h>

typedef unsigned short u16;
typedef float f32x4 __attribute__((ext_vector_type(4)));
typedef short bf16x8 __attribute__((ext_vector_type(8)));

constexpr int SH = 9;          // 512 nodes per bucket
constexpr int NB = 1 << SH;    // 512
constexpr int TILE = 4096;     // edges per partition block

__device__ inline float bf2f(u16 u) {
  union { unsigned int i; float f; } c;
  c.i = ((unsigned int)u) << 16;
  return c.f;
}
__device__ inline u16 f2bf(float f) {
  union { float f; unsigned int i; } c;
  c.f = f;
  unsigned int r = c.i + 0x7fff + ((c.i >> 16) & 1);  // RNE
  return (u16)(r >> 16);
}

union V8 {
  bf16x8 v;
  short s[8];
  u16 u[8];
};

// ---------------- graph build: tiled counting sort ----------------

__global__ void __launch_bounds__(256) k_hist(const int* __restrict__ dst,
                                              int* __restrict__ ghist, int E,
                                              int nblk, int nbk) {
  __shared__ int lcnt[NB];
  int t = threadIdx.x, blk = blockIdx.x;
  for (int i = t; i < nbk; i += 256) lcnt[i] = 0;
  __syncthreads();
  int beg = blk * TILE, end = min(beg + TILE, E);
  int vend = beg + ((end - beg) & ~3);
  for (int e = beg + t * 4; e + 4 <= vend; e += 1024) {
    int4 d4 = *(const int4*)&dst[e];
    atomicAdd(&lcnt[d4.x >> SH], 1);
    atomicAdd(&lcnt[d4.y >> SH], 1);
    atomicAdd(&lcnt[d4.z >> SH], 1);
    atomicAdd(&lcnt[d4.w >> SH], 1);
  }
  for (int e = vend + t; e < end; e += 256) atomicAdd(&lcnt[dst[e] >> SH], 1);
  __syncthreads();
  for (int i = t; i < nbk; i += 256) ghist[i * nblk + blk] = lcnt[i];
}

// per-bucket row scan: exclusive within row, row total -> bsum[bucket]
__global__ void __launch_bounds__(256) k_scanA(int* __restrict__ ghist,
                                               int* __restrict__ bsum, int nblk) {
  __shared__ int sc[256];
  int i = blockIdx.x, t = threadIdx.x;
  int* row = ghist + (size_t)i * nblk;
  int e0 = 2 * t, e1 = 2 * t + 1;
  int a0 = (e0 < nblk) ? row[e0] : 0;
  int a1 = (e1 < nblk) ? row[e1] : 0;
  int s = a0 + a1;
  sc[t] = s;
  __syncthreads();
  for (int o = 1; o < 256; o <<= 1) {
    int x = (t >= o) ? sc[t - o] : 0;
    __syncthreads();
    sc[t] += x;
    __syncthreads();
  }
  int base = sc[t] - s;  // exclusive
  if (e0 < nblk) row[e0] = base;
  if (e1 < nblk) row[e1] = base + a0;
  if (t == 255) bsum[i] = sc[255];
}

// partition: scatter packed (src | localdst<<20) into bucket-contiguous runs.
__global__ void __launch_bounds__(256) k_part(const int* __restrict__ src,
                                              const int* __restrict__ dst,
                                              const int* __restrict__ goff,
                                              const int* __restrict__ bsum,
                                              int* __restrict__ ebuf, int E,
                                              int nblk, int nbk) {
  __shared__ int lcur[NB];
  __shared__ int sb[256];
  int t = threadIdx.x, blk = blockIdx.x;
  int v = (t < nbk) ? bsum[t] : 0;
  sb[t] = v;
  __syncthreads();
  for (int o = 1; o < 256; o <<= 1) {
    int x = (t >= o) ? sb[t - o] : 0;
    __syncthreads();
    sb[t] += x;
    __syncthreads();
  }
  for (int i = t; i < nbk; i += 256)
    lcur[i] = goff[(size_t)i * nblk + blk] + (i ? sb[i - 1] : 0);
  __syncthreads();
  int beg = blk * TILE, end = min(beg + TILE, E);
  int vend = beg + ((end - beg) & ~3);
  for (int e = beg + t * 4; e + 4 <= vend; e += 1024) {
    int4 s4 = *(const int4*)&src[e];
    int4 d4 = *(const int4*)&dst[e];
    int p0 = atomicAdd(&lcur[d4.x >> SH], 1);
    ebuf[p0] = s4.x | ((d4.x & (NB - 1)) << 20);
    int p1 = atomicAdd(&lcur[d4.y >> SH], 1);
    ebuf[p1] = s4.y | ((d4.y & (NB - 1)) << 20);
    int p2 = atomicAdd(&lcur[d4.z >> SH], 1);
    ebuf[p2] = s4.z | ((d4.z & (NB - 1)) << 20);
    int p3 = atomicAdd(&lcur[d4.w >> SH], 1);
    ebuf[p3] = s4.w | ((d4.w & (NB - 1)) << 20);
  }
  for (int e = vend + t; e < end; e += 256) {
    int s = src[e], d = dst[e];
    int p = atomicAdd(&lcur[d >> SH], 1);
    ebuf[p] = s | ((d & (NB - 1)) << 20);
  }
}

// one block per bucket: exact CSR + dinv, bookkeeping in LDS
__global__ void __launch_bounds__(256) k_refine(
    const int* __restrict__ ebuf, const int* __restrict__ goff,
    const int* __restrict__ bsum, int* __restrict__ rowptr,
    int* __restrict__ colsrc, float* __restrict__ dinv,
    int n, int nbk, int nblk, int E) {
  __shared__ int cnt[NB];
  __shared__ int cur[NB];
  __shared__ int sc[256];
  __shared__ int bex[256];
  int b = blockIdx.x, t = threadIdx.x;
  {
    int v = (t < nbk) ? bsum[t] : 0;
    bex[t] = v;
    __syncthreads();
    for (int o = 1; o < 256; o <<= 1) {
      int x = (t >= o) ? bex[t - o] : 0;
      __syncthreads();
      bex[t] += x;
      __syncthreads();
    }
  }
  int beg = goff[(size_t)b * nblk] + (b ? bex[b - 1] : 0);
  int end = (b + 1 < nbk) ? goff[(size_t)(b + 1) * nblk] + bex[b] : E;
  cnt[t] = 0;
  cnt[t + 256] = 0;
  __syncthreads();
  for (int i = beg + t; i < end; i += 256) atomicAdd(&cnt[ebuf[i] >> 20], 1);
  __syncthreads();
  int c0 = cnt[2 * t], c1 = cnt[2 * t + 1];
  int a = c0 + c1;
  sc[t] = a;
  __syncthreads();
  for (int o = 1; o < 256; o <<= 1) {
    int x = (t >= o) ? sc[t - o] : 0;
    __syncthreads();
    sc[t] += x;
    __syncthreads();
  }
  int base0 = beg + sc[t] - a;
  int base1 = base0 + c0;
  int node0 = b << SH;
  int n0 = node0 + 2 * t, n1 = n0 + 1;
  cur[2 * t] = base0;
  cur[2 * t + 1] = base1;
  if (n0 <= n) rowptr[n0] = base0;
  if (n1 <= n) rowptr[n1] = base1;
  if (n0 < n) dinv[n0] = rsqrtf((float)(c0 + 1));
  if (n1 < n) dinv[n1] = rsqrtf((float)(c1 + 1));
  if (b == nbk - 1 && t == 0) rowptr[n] = E;
  __syncthreads();
  for (int i = beg + t; i < end; i += 256) {
    int w = ebuf[i];
    int p = atomicAdd(&cur[w >> 20], 1);
    colsrc[p] = w & 0xFFFFF;
  }
}

// ---------------- MFMA dense transform (layer 1 only) ----------------

template <int KC, int FOUT, bool BF16IN>
__global__ void __launch_bounds__(256) k_xform(
    const void* __restrict__ xin, const float* __restrict__ Wg,
    const float* __restrict__ dinv, u16* __restrict__ g, int n) {
  constexpr int FIN = KC * 32;
  constexpr int NC = FOUT / 16;
  constexpr int ASLOTS = 8 * KC * 64;
  constexpr int WSLOTS = KC * NC * 64;
  __shared__ short xa[ASLOTS * 8];
  __shared__ short wb[WSLOTS * 8];

  int t = threadIdx.x;
  int r0 = blockIdx.x * 128;

  for (int s = t; s < WSLOTS; s += 256) {
    int lane = s & 63, q = s >> 6;
    int nc = q % NC, kc = q / NC;
    int col = nc * 16 + (lane & 15);
    int kr = kc * 32 + (lane >> 4) * 8;
    V8 v;
#pragma unroll
    for (int j = 0; j < 8; ++j) v.s[j] = (short)f2bf(Wg[(kr + j) * FOUT + col]);
    *(bf16x8*)&wb[s * 8] = v.v;
  }

  for (int s = t; s < ASLOTS; s += 256) {
    int lane = s & 63, q = s >> 6;
    int kc = q % KC, mtile = q / KC;
    int row = mtile * 16 + (lane & 15);
    int k = kc * 32 + (lane >> 4) * 8;
    int gr = r0 + row;
    V8 v;
    if (gr < n) {
      if constexpr (BF16IN) {
        v.v = *(const bf16x8*)((const u16*)xin + (size_t)gr * FIN + k);
      } else {
        const float* xf = (const float*)xin + (size_t)gr * FIN + k;
        float4 p = *(const float4*)xf;
        float4 q4 = *(const float4*)(xf + 4);
        v.s[0] = (short)f2bf(p.x); v.s[1] = (short)f2bf(p.y);
        v.s[2] = (short)f2bf(p.z); v.s[3] = (short)f2bf(p.w);
        v.s[4] = (short)f2bf(q4.x); v.s[5] = (short)f2bf(q4.y);
        v.s[6] = (short)f2bf(q4.z); v.s[7] = (short)f2bf(q4.w);
      }
    } else {
      for (int j = 0; j < 8; ++j) v.s[j] = 0;
    }
    *(bf16x8*)&xa[s * 8] = v.v;
  }
  __syncthreads();

  int ln = t & 63, wv = t >> 6;
  int m0 = wv * 2;

  bf16x8 bf[KC * NC];
#pragma unroll
  for (int i = 0; i < KC * NC; ++i) bf[i] = *(const bf16x8*)&wb[(i * 64 + ln) * 8];

  f32x4 acc[2][NC];
#pragma unroll
  for (int i = 0; i < 2; ++i)
#pragma unroll
    for (int j = 0; j < NC; ++j) acc[i][j] = {0.f, 0.f, 0.f, 0.f};

#pragma unroll
  for (int kc = 0; kc < KC; ++kc) {
    bf16x8 a0 = *(const bf16x8*)&xa[(((m0 + 0) * KC + kc) * 64 + ln) * 8];
    bf16x8 a1 = *(const bf16x8*)&xa[(((m0 + 1) * KC + kc) * 64 + ln) * 8];
#pragma unroll
    for (int nc = 0; nc < NC; ++nc) {
      acc[0][nc] = __builtin_amdgcn_mfma_f32_16x16x32_bf16(a0, bf[kc * NC + nc], acc[0][nc], 0, 0, 0);
      acc[1][nc] = __builtin_amdgcn_mfma_f32_16x16x32_bf16(a1, bf[kc * NC + nc], acc[1][nc], 0, 0, 0);
    }
  }

  int colb = ln & 15, rq = ln >> 4;
#pragma unroll
  for (int mt2 = 0; mt2 < 2; ++mt2) {
#pragma unroll
    for (int reg = 0; reg < 4; ++reg) {
      int gr = r0 + (m0 + mt2) * 16 + rq * 4 + reg;
      if (gr < n) {
        float di = dinv[gr];
#pragma unroll
        for (int nc = 0; nc < NC; ++nc)
          g[(size_t)gr * FOUT + nc * 16 + colb] = f2bf(acc[mt2][nc][reg] * di);
      }
    }
  }
}

// ---------------- fused gather + finalize + next-transform + FC slice ----------
// champion r8 form: 256 threads / 4 waves, 128 rows per block.

template <int GF, int GOUT, int FCROW0, int FCROWS, int MODE>
__global__ void __launch_bounds__(256) k_gx(
    const u16* __restrict__ gin, const int* __restrict__ rowptr,
    const int* __restrict__ colsrc, const float* __restrict__ dinv,
    const float* __restrict__ bias, const float* __restrict__ Wg,
    const float* __restrict__ Wfc, const float* __restrict__ bfc,
    u16* __restrict__ gout, float* __restrict__ out, int n) {
  constexpr int KC = (GF + 31) / 32;
  constexpr int NCG = (GOUT > 0) ? (GOUT / 16) : 1;
  constexpr int ASLOTS = 8 * KC * 64;
  constexpr int WGSLOTS = (GOUT > 0) ? (KC * NCG * 64) : 64;
  constexpr int WFSLOTS = KC * 64;
  __shared__ short xa[ASLOTS * 8];
  __shared__ short wgb[WGSLOTS * 8];
  __shared__ short wfb[WFSLOTS * 8];

  int t = threadIdx.x;
  int r0 = blockIdx.x * 128;

  {
    V8 z;
#pragma unroll
    for (int j = 0; j < 8; ++j) z.s[j] = 0;
    for (int s = t; s < ASLOTS; s += 256) *(bf16x8*)&xa[s * 8] = z.v;
  }
  if constexpr (GOUT > 0) {
    for (int s = t; s < WGSLOTS; s += 256) {
      int lane = s & 63, q = s >> 6;
      int nc = q % NCG, kc = q / NCG;
      int col = nc * 16 + (lane & 15);
      int kr = kc * 32 + (lane >> 4) * 8;
      V8 v;
#pragma unroll
      for (int j = 0; j < 8; ++j) v.s[j] = (short)f2bf(Wg[(kr + j) * GOUT + col]);
      *(bf16x8*)&wgb[s * 8] = v.v;
    }
  }
  for (int s = t; s < WFSLOTS; s += 256) {
    int lane = s & 63, kc = s >> 6;
    int col = lane & 15;
    int kr = kc * 32 + (lane >> 4) * 8;
    V8 v;
#pragma unroll
    for (int j = 0; j < 8; ++j)
      v.s[j] = (kr + j < FCROWS) ? (short)f2bf(Wfc[(FCROW0 + kr + j) * 16 + col]) : (short)0;
    *(bf16x8*)&wfb[s * 8] = v.v;
  }
  __syncthreads();

  // ---- gather phase: 16B/lane, GF/8 lanes per node, 4-way edge unroll
  {
    constexpr int LPG = GF / 8;
    constexpr int NPW = 64 / LPG;           // nodes per wave per pass
    constexpr int PASSES = 128 / (NPW * 4); // 4 waves per block
    int ln = t & 63, wib = t >> 6;
    int lanein = ln % LPG, grp = ln / LPG;
    int f0 = lanein * 8;
    float bb[8];
#pragma unroll
    for (int j = 0; j < 8; ++j) bb[j] = bias[f0 + j];
#pragma unroll
    for (int pass = 0; pass < PASSES; ++pass) {
      int lr = pass * (NPW * 4) + wib * NPW + grp;
      int gr = r0 + lr;
      if (gr < n) {
        int b = rowptr[gr], e = rowptr[gr + 1];
        float p0[8], p1[8], p2[8], p3[8];
        {
          V8 u;
          u.v = *(const bf16x8*)&gin[(size_t)gr * GF + f0];  // self-loop
#pragma unroll
          for (int j = 0; j < 8; ++j) {
            p0[j] = bf2f(u.u[j]);
            p1[j] = 0.f; p2[j] = 0.f; p3[j] = 0.f;
          }
        }
        int i = b;
        for (; i + 4 <= e; i += 4) {
          int s0 = colsrc[i + 0], s1 = colsrc[i + 1];
          int s2 = colsrc[i + 2], s3 = colsrc[i + 3];
          V8 u0, u1, u2, u3;
          u0.v = *(const bf16x8*)&gin[(size_t)s0 * GF + f0];
          u1.v = *(const bf16x8*)&gin[(size_t)s1 * GF + f0];
          u2.v = *(const bf16x8*)&gin[(size_t)s2 * GF + f0];
          u3.v = *(const bf16x8*)&gin[(size_t)s3 * GF + f0];
#pragma unroll
          for (int j = 0; j < 8; ++j) {
            p0[j] += bf2f(u0.u[j]);
            p1[j] += bf2f(u1.u[j]);
            p2[j] += bf2f(u2.u[j]);
            p3[j] += bf2f(u3.u[j]);
          }
        }
        for (; i < e; ++i) {
          int s = colsrc[i];
          V8 u;
          u.v = *(const bf16x8*)&gin[(size_t)s * GF + f0];
#pragma unroll
          for (int j = 0; j < 8; ++j) p1[j] += bf2f(u.u[j]);
        }
        float di = dinv[gr];
        V8 o;
#pragma unroll
        for (int j = 0; j < 8; ++j) {
          float a = (p0[j] + p1[j]) + (p2[j] + p3[j]);
          o.u[j] = f2bf(fmaxf(fmaf(a, di, bb[j]), 0.f));
        }
        int kc = f0 >> 5, q = (f0 >> 3) & 3;
        int slot = ((lr >> 4) * KC + kc) * 64 + ((lr & 15) | (q << 4));
        *(bf16x8*)&xa[slot * 8] = o.v;
      }
    }
  }
  __syncthreads();

  // ---- MFMA phase: 4 waves, two 16-row m-tiles each
  int ln = t & 63, wv = t >> 6;
  int m0 = wv * 2;

  bf16x8 wgf[KC * NCG];
  if constexpr (GOUT > 0) {
#pragma unroll
    for (int i = 0; i < KC * NCG; ++i) wgf[i] = *(const bf16x8*)&wgb[(i * 64 + ln) * 8];
  }
  bf16x8 wff[KC];
#pragma unroll
  for (int i = 0; i < KC; ++i) wff[i] = *(const bf16x8*)&wfb[(i * 64 + ln) * 8];

  f32x4 accG[2][NCG];
  f32x4 accF[2];
#pragma unroll
  for (int i = 0; i < 2; ++i) {
    accF[i] = {0.f, 0.f, 0.f, 0.f};
#pragma unroll
    for (int j = 0; j < NCG; ++j) accG[i][j] = {0.f, 0.f, 0.f, 0.f};
  }

#pragma unroll
  for (int kc = 0; kc < KC; ++kc) {
    bf16x8 a0 = *(const bf16x8*)&xa[(((m0 + 0) * KC + kc) * 64 + ln) * 8];
    bf16x8 a1 = *(const bf16x8*)&xa[(((m0 + 1) * KC + kc) * 64 + ln) * 8];
    if constexpr (GOUT > 0) {
#pragma unroll
      for (int nc = 0; nc < NCG; ++nc) {
        accG[0][nc] = __builtin_amdgcn_mfma_f32_16x16x32_bf16(a0, wgf[kc * NCG + nc], accG[0][nc], 0, 0, 0);
        accG[1][nc] = __builtin_amdgcn_mfma_f32_16x16x32_bf16(a1, wgf[kc * NCG + nc], accG[1][nc], 0, 0, 0);
      }
    }
    accF[0] = __builtin_amdgcn_mfma_f32_16x16x32_bf16(a0, wff[kc], accF[0], 0, 0, 0);
    accF[1] = __builtin_amdgcn_mfma_f32_16x16x32_bf16(a1, wff[kc], accF[1], 0, 0, 0);
  }

  int colb = ln & 15, rq = ln >> 4;
#pragma unroll
  for (int mt2 = 0; mt2 < 2; ++mt2) {
#pragma unroll
    for (int reg = 0; reg < 4; ++reg) {
      int gr = r0 + (m0 + mt2) * 16 + rq * 4 + reg;
      if (gr < n) {
        if constexpr (GOUT > 0) {
          float di = dinv[gr];
#pragma unroll
          for (int nc = 0; nc < NCG; ++nc)
            gout[(size_t)gr * GOUT + nc * 16 + colb] = f2bf(accG[mt2][nc][reg] * di);
        }
        float fcv = accF[mt2][reg];
        size_t oi = (size_t)gr * 16 + colb;
        if constexpr (MODE == 0) {
          out[oi] = fcv;
        } else if constexpr (MODE == 1) {
          out[oi] += fcv;
        } else {
          out[oi] = fmaxf(out[oi] + fcv + bfc[colb], 0.f);
        }
      }
    }
  }
}

// ---------------- launch ----------------

extern "C" void kernel_launch(void* const* d_in, const int* in_sizes, int n_in,
                              void* d_out, int out_size, void* d_ws, size_t ws_size,
                              hipStream_t stream) {
  const int* edges = (const int*)d_in[0];
  const float* feat = (const float*)d_in[1];
  const float* W1 = (const float*)d_in[2];
  const float* b1 = (const float*)d_in[3];
  const float* W2 = (const float*)d_in[4];
  const float* b2 = (const float*)d_in[5];
  const float* W3 = (const float*)d_in[6];
  const float* b3 = (const float*)d_in[7];
  const float* Wfc = (const float*)d_in[8];
  const float* bfc = (const float*)d_in[9];
  float* out = (float*)d_out;

  const int E = in_sizes[0] / 2;
  const int n = in_sizes[1] / 128;
  const int* srcp = edges;
  const int* dstp = edges + E;
  const int nbk = (n + NB - 1) >> SH;          // 196 (<=256)
  const int nblk = (E + TILE - 1) / TILE;      // 391 (<=512)

  char* w = (char*)d_ws;
  auto carve = [&](size_t bytes) {
    void* p = (void*)w;
    w += (bytes + 255) & ~(size_t)255;
    return p;
  };
  int* ghist = (int*)carve((size_t)nbk * nblk * 4);
  int* bsum = (int*)carve(256 * 4);
  int* rowptr = (int*)carve(((size_t)n + 1) * 4);
  float* dinv = (float*)carve((size_t)n * 4);
  int* colsrc = (int*)carve((size_t)E * 4);
  size_t big = (size_t)E * 4 > (size_t)n * 128 ? (size_t)E * 4 : (size_t)n * 128;
  void* shared_big = carve(big);
  int* ebuf = (int*)shared_big;
  u16* g1 = (u16*)shared_big;
  u16* g3 = (u16*)shared_big;
  u16* g2 = (u16*)carve((size_t)n * 32 * 2);

  k_hist<<<nblk, 256, 0, stream>>>(dstp, ghist, E, nblk, nbk);
  k_scanA<<<nbk, 256, 0, stream>>>(ghist, bsum, nblk);
  k_part<<<nblk, 256, 0, stream>>>(srcp, dstp, ghist, bsum, ebuf, E, nblk, nbk);
  k_refine<<<nbk, 256, 0, stream>>>(ebuf, ghist, bsum, rowptr, colsrc, dinv, n, nbk, nblk, E);

  const int xb = (n + 127) / 128;  // 782

  k_xform<4, 64, false><<<xb, 256, 0, stream>>>(feat, W1, dinv, g1, n);
  k_gx<64, 32, 0, 64, 0><<<xb, 256, 0, stream>>>(
      g1, rowptr, colsrc, dinv, b1, W2, Wfc, bfc, g2, out, n);
  k_gx<32, 16, 64, 32, 1><<<xb, 256, 0, stream>>>(
      g2, rowptr, colsrc, dinv, b2, W3, Wfc, bfc, g3, out, n);
  k_gx<16, 0, 96, 16, 2><<<xb, 256, 0, stream>>>(
      g3, rowptr, colsrc, dinv, b3, (const float*)nullptr, Wfc, bfc,
      (u16*)nullptr, out, n);
}